// Round 2
// baseline (595.865 us; speedup 1.0000x reference)
//
#include <hip/hip_runtime.h>
#include <math.h>

#define FDIM 32
#define NBASIS 8
#define QP 40     // A-stage row pad (f16 units) -> 80B rows, 16B-aligned quads
#define DS 18     // bwd D-stage stride (uints): (8*DS)%32=16 -> 2-way bank aliasing (free)
#define SCH 4096  // scan chunk per block (256 thr x 16)

constexpr float RCUT_C = 20.0f;
constexpr float PI_F = 3.14159265358979323846f;
constexpr float EV2KJ_C = 96.4853f;
constexpr float NM2A_C = 10.0f;

typedef _Float16 f16x8 __attribute__((ext_vector_type(8)));
typedef _Float16 f16x4 __attribute__((ext_vector_type(4)));
typedef float f32x4 __attribute__((ext_vector_type(4)));

__device__ __forceinline__ float sigmoidf_(float z) { return 1.0f / (1.0f + __expf(-z)); }

__device__ __forceinline__ unsigned int pk2_(float a, float b) {
    unsigned short lo = __builtin_bit_cast(unsigned short, (_Float16)a);
    unsigned short hi = __builtin_bit_cast(unsigned short, (_Float16)b);
    return (unsigned int)lo | ((unsigned int)hi << 16);
}
__device__ __forceinline__ float lo16_(unsigned int v) {
    return (float)__builtin_bit_cast(_Float16, (unsigned short)(v & 0xffffu));
}
__device__ __forceinline__ float hi16_(unsigned int v) {
    return (float)__builtin_bit_cast(_Float16, (unsigned short)(v >> 16));
}

// ---------------- CSR build: dual histogram (dst + src), 3-kernel scan, scatter ----------------
__global__ __launch_bounds__(256) void hist_dst(
    const int* __restrict__ eidx, int* __restrict__ counts, int E, int N)
{
    for (int e = blockIdx.x * 256 + threadIdx.x; e < E; e += gridDim.x * 256) {
        int s = eidx[e];
        int d = eidx[E + e];
        atomicAdd(&counts[d], 1);
        atomicAdd(&counts[N + s], 1);
    }
}

__global__ __launch_bounds__(256) void scan_partial(
    const int* __restrict__ counts, int* __restrict__ bsum, int NN)
{
    __shared__ int red[256];
    const int t = threadIdx.x;
    const int st = blockIdx.x * SCH + t * 16;
    int s = 0;
    #pragma unroll
    for (int i = 0; i < 16; i++) { int idx = st + i; if (idx < NN) s += counts[idx]; }
    red[t] = s;
    __syncthreads();
    for (int k = 128; k; k >>= 1) {
        if (t < k) red[t] += red[t + k];
        __syncthreads();
    }
    if (t == 0) bsum[blockIdx.x] = red[0];
}

__global__ __launch_bounds__(64) void scan_bsum(int* __restrict__ bsum, int nb)
{
    if (threadIdx.x == 0) {
        int run = 0;
        for (int i = 0; i < nb; i++) { int v = bsum[i]; bsum[i] = run; run += v; }
    }
}

__global__ __launch_bounds__(256) void scan_write(
    const int* __restrict__ counts, const int* __restrict__ bsum,
    int* __restrict__ cursor, int NN)
{
    __shared__ int lds[256];
    const int t = threadIdx.x;
    const int st = blockIdx.x * SCH + t * 16;
    int vals[16];
    int s = 0;
    #pragma unroll
    for (int i = 0; i < 16; i++) {
        int idx = st + i;
        int v = (idx < NN) ? counts[idx] : 0;
        vals[i] = v; s += v;
    }
    lds[t] = s;
    __syncthreads();
    for (int off = 1; off < 256; off <<= 1) {
        int v = (t >= off) ? lds[t - off] : 0;
        __syncthreads();
        lds[t] += v;
        __syncthreads();
    }
    int run = bsum[blockIdx.x] + lds[t] - s;   // exclusive prefix
    #pragma unroll
    for (int i = 0; i < 16; i++) {
        int idx = st + i;
        if (idx < NN) cursor[idx] = run;
        run += vals[i];
    }
}

// order_sd[p] in dst-sorted order; epos[src-sorted pos] = dst-sorted pos
__global__ __launch_bounds__(256) void scatter_edges(
    const int* __restrict__ eidx, int* __restrict__ cursor,
    int2* __restrict__ order_sd, int* __restrict__ epos, int E, int N)
{
    for (int e = blockIdx.x * 256 + threadIdx.x; e < E; e += gridDim.x * 256) {
        int s = eidx[e];
        int d = eidx[E + e];
        int p = atomicAdd(&cursor[d], 1);
        order_sd[p] = make_int2(s, d);
        int p2 = atomicAdd(&cursor[N + s], 1) - E;
        epos[p2] = p;
    }
}

// ---------------- weight fragment pre-pack: per-lane MFMA B operands ----------------
// Layout per lane (64 f16 = 128B): [0:8)=bz0 [8:16)=bz1 [16:24)=bf0 [24:32)=bf1
//                                  [32:40)=bf2 [40:48)=bf3 [48:56)=bt0 [56:64)=bt1
__global__ __launch_bounds__(64) void pack_wfrag(
    const float* __restrict__ Wr1, const float* __restrict__ Wr2,
    _Float16* __restrict__ wpack)
{
    const int lane = threadIdx.x;          // 0..63
    const int kb = (lane >> 4) * 8, nb = lane & 15;
    _Float16* o = wpack + (size_t)lane * 64;
    #pragma unroll
    for (int t = 0; t < 2; t++)
        #pragma unroll
        for (int j = 0; j < 8; j++) {
            int k = kb + j;
            o[t * 8 + j] = (k < 8) ? (_Float16)Wr1[k * FDIM + t * 16 + nb] : (_Float16)0.0f;
        }
    #pragma unroll
    for (int t = 0; t < 4; t++)
        #pragma unroll
        for (int j = 0; j < 8; j++)
            o[16 + t * 8 + j] = (_Float16)Wr2[(kb + j) * 64 + t * 16 + nb];
    #pragma unroll
    for (int t = 0; t < 2; t++)
        #pragma unroll
        for (int j = 0; j < 8; j++) {
            int k = kb + j;
            o[48 + t * 8 + j] = (k >= 8 && k < 16) ? (_Float16)Wr1[(k - 8) * FDIM + t * 16 + nb]
                                                   : (_Float16)0.0f;
        }
}

// ---------------- edge forward: hs*env folded into packed D; LDS-stashed keys ----------------
__global__ __launch_bounds__(256) void edge_fwd_mfma(
    const float* __restrict__ pos, const int* __restrict__ types,
    const int2* __restrict__ order_sd,
    const _Float16* __restrict__ wpack, const float* __restrict__ br1,
    const float* __restrict__ temb,
    float* __restrict__ s_acc, float* __restrict__ v_acc, int E)
{
    __shared__ __align__(16) _Float16 sR[4][2560];
    __shared__ float sSt[4][32][4];         // env, rhx, rhy, rhz
    __shared__ int sTy[4][32];
    __shared__ int sKey[4][32];
    __shared__ float sTemb[96];

    const int lane = threadIdx.x & 63;
    const int l32 = threadIdx.x & 31;
    const int hw = (threadIdx.x >> 5) & 1;
    const int w = threadIdx.x >> 6;
    const int gbase = blockIdx.x * 128 + w * 32;

    for (int i = threadIdx.x; i < 96; i += 256) sTemb[i] = temb[i];
    __syncthreads();

    const int kb = (lane >> 4) * 8;
    // vector-load prepacked B fragments (6 x 16B, coalesced, L2-resident)
    const f16x8* wp = (const f16x8*)(wpack + (size_t)lane * 64);
    f16x8 bz[2] = { wp[0], wp[1] };
    f16x8 bf[4] = { wp[2], wp[3], wp[4], wp[5] };

    // ---- phase 0: lane-parallel geometry + basis (lanes 0..31) ----
    if (lane < 32) {
        const int ed = l32;
        const int p = gbase + ed;
        const bool vld = (p < E);
        int2 sd = vld ? order_sd[p] : make_int2(0, 0);
        float rx = (pos[sd.y * 3 + 0] - pos[sd.x * 3 + 0]) * NM2A_C;
        float ry = (pos[sd.y * 3 + 1] - pos[sd.x * 3 + 1]) * NM2A_C;
        float rz = (pos[sd.y * 3 + 2] - pos[sd.x * 3 + 2]) * NM2A_C;
        float r2 = rx * rx + ry * ry + rz * rz + 1e-12f;
        float r = sqrtf(r2);
        float rinv = 1.0f / r;
        float x = r * (1.0f / RCUT_C);
        float x2 = x * x, x4 = x2 * x2, x6 = x4 * x2, x7 = x6 * x, x8 = x6 * x2;
        float env = (x < 1.0f) ? (1.0f - 28.0f * x6 + 48.0f * x7 - 21.0f * x8) : 0.0f;

        float th = PI_F * x, s1, c1;
        __sincosf(th, &s1, &c1);
        float sp = 0.0f, sn = s1;
        _Float16 av[8];
        #pragma unroll
        for (int n = 0; n < NBASIS; n++) {
            av[n] = (_Float16)(sn * rinv);
            float snx = 2.0f * c1 * sn - sp; sp = sn; sn = snx;
        }
        _Float16* dstA = &sR[w][(ed < 16 ? 0 : 640) + (ed & 15) * QP];
        *(f16x8*)&dstA[0] = *(f16x8*)&av[0];
        *(float4*)&dstA[8]  = make_float4(0.f, 0.f, 0.f, 0.f);
        *(float4*)&dstA[16] = make_float4(0.f, 0.f, 0.f, 0.f);
        *(float4*)&dstA[24] = make_float4(0.f, 0.f, 0.f, 0.f);
        sSt[w][ed][0] = env;
        sSt[w][ed][1] = rx * rinv;
        sSt[w][ed][2] = ry * rinv;
        sSt[w][ed][3] = rz * rinv;
        sTy[w][ed] = types[sd.x];
        sKey[w][ed] = vld ? sd.y : -1;
    }

    // ---- phase 1: MFMA basis layer -> z, silu -> Q (both tiles) ----
    {
        const int me = lane & 15;
        f16x8 a1a = *(const f16x8*)&sR[w][me * QP + kb];
        f16x8 a1b = *(const f16x8*)&sR[w][640 + me * QP + kb];
        const f32x4 z4 = {0.f, 0.f, 0.f, 0.f};
        f32x4 Dz0a = __builtin_amdgcn_mfma_f32_16x16x32_f16(a1a, bz[0], z4, 0, 0, 0);
        f32x4 Dz1a = __builtin_amdgcn_mfma_f32_16x16x32_f16(a1a, bz[1], z4, 0, 0, 0);
        f32x4 Dz0b = __builtin_amdgcn_mfma_f32_16x16x32_f16(a1b, bz[0], z4, 0, 0, 0);
        f32x4 Dz1b = __builtin_amdgcn_mfma_f32_16x16x32_f16(a1b, bz[1], z4, 0, 0, 0);
        const int f0 = lane & 15, e0 = (lane >> 4) * 4;
        const float bb0 = br1[f0], bb1 = br1[16 + f0];
        #pragma unroll
        for (int t = 0; t < 2; t++) {
            f32x4 Dza = t ? Dz1a : Dz0a;
            f32x4 Dzb = t ? Dz1b : Dz0b;
            float bb = t ? bb1 : bb0;
            #pragma unroll
            for (int r = 0; r < 4; r++) {
                float za = Dza[r] + bb;
                float zb = Dzb[r] + bb;
                sR[w][1280 + (e0 + r) * QP + t * 16 + f0] = (_Float16)(za * sigmoidf_(za));
                sR[w][1920 + (e0 + r) * QP + t * 16 + f0] = (_Float16)(zb * sigmoidf_(zb));
            }
        }
    }

    // ---- phase 2: MFMA W2; fold hs*env; pack (ch, ch+32) pairs; D[edge*32+ch] ----
    {
        const int me = lane & 15;
        f16x8 aqa = *(const f16x8*)&sR[w][1280 + me * QP + kb];
        f16x8 aqb = *(const f16x8*)&sR[w][1920 + me * QP + kb];
        const int cb = lane & 15, e0 = (lane >> 4) * 4;
        float hev[2][2][4];   // [tile][fpair][r] = hs(ch)*env
        #pragma unroll
        for (int tl = 0; tl < 2; tl++)
            #pragma unroll
            for (int fp = 0; fp < 2; fp++)
                #pragma unroll
                for (int r = 0; r < 4; r++) {
                    int ed = tl * 16 + e0 + r;
                    hev[tl][fp][r] = sTemb[sTy[w][ed] * 32 + fp * 16 + cb] * sSt[w][ed][0];
                }
        const f32x4 z4 = {0.f, 0.f, 0.f, 0.f};
        unsigned int* DU = (unsigned int*)&sR[w][0];
        #pragma unroll
        for (int fp = 0; fp < 2; fp++) {
            f32x4 a0 = __builtin_amdgcn_mfma_f32_16x16x32_f16(aqa, bf[fp],     z4, 0, 0, 0);
            f32x4 a1 = __builtin_amdgcn_mfma_f32_16x16x32_f16(aqa, bf[fp + 2], z4, 0, 0, 0);
            f32x4 b0 = __builtin_amdgcn_mfma_f32_16x16x32_f16(aqb, bf[fp],     z4, 0, 0, 0);
            f32x4 b1 = __builtin_amdgcn_mfma_f32_16x16x32_f16(aqb, bf[fp + 2], z4, 0, 0, 0);
            #pragma unroll
            for (int r = 0; r < 4; r++) {
                float ha = hev[0][fp][r], hb = hev[1][fp][r];
                DU[(e0 + r) * 32 + fp * 16 + cb]        = pk2_(a0[r] * ha, a1[r] * ha);
                DU[(16 + e0 + r) * 32 + fp * 16 + cb]   = pk2_(b0[r] * hb, b1[r] * hb);
            }
        }
    }

    // ---- phase 3: epilogue, run-merge carried across both tiles (keys from LDS) ----
    const unsigned int* DU = (const unsigned int*)&sR[w][0];
    int runKey = -1;
    float sAcc = 0.f, vXA = 0.f, vYA = 0.f, vZA = 0.f;
    #pragma unroll
    for (int t = 0; t < 2; t++) {
        #pragma unroll
        for (int i = 0; i < 8; i++) {
            const int m = t * 16 + hw * 8 + i;
            const int p = gbase + m;
            if (p >= E) break;
            int k = sKey[w][m];
            if (k != runKey) {
                if (runKey >= 0) {
                    unsafeAtomicAdd(&s_acc[(size_t)runKey * 32 + l32], sAcc);
                    unsafeAtomicAdd(&v_acc[(size_t)runKey * 96 + 0 * 32 + l32], vXA);
                    unsafeAtomicAdd(&v_acc[(size_t)runKey * 96 + 1 * 32 + l32], vYA);
                    unsafeAtomicAdd(&v_acc[(size_t)runKey * 96 + 2 * 32 + l32], vZA);
                }
                runKey = k;
                sAcc = vXA = vYA = vZA = 0.f;
            }
            unsigned int qp = DU[m * 32 + l32];
            float s0 = lo16_(qp);       // hs*env*rw0
            float h1 = hi16_(qp);       // hs*env*rw1
            sAcc += s0;
            vXA += h1 * sSt[w][m][1];
            vYA += h1 * sSt[w][m][2];
            vZA += h1 * sSt[w][m][3];
        }
    }
    if (runKey >= 0) {
        unsafeAtomicAdd(&s_acc[(size_t)runKey * 32 + l32], sAcc);
        unsafeAtomicAdd(&v_acc[(size_t)runKey * 96 + 0 * 32 + l32], vXA);
        unsafeAtomicAdd(&v_acc[(size_t)runKey * 96 + 1 * 32 + l32], vYA);
        unsafeAtomicAdd(&v_acc[(size_t)runKey * 96 + 2 * 32 + l32], vZA);
    }
}

// -------- atom MLP: 64 atoms/block; packed g_all writes; energy fused (atomic) --------
__global__ __launch_bounds__(256) void atom_mlp(
    const int* __restrict__ types, const float* __restrict__ temb,
    const float* __restrict__ Wself, const float* __restrict__ Wo1,
    const float* __restrict__ bo1, const float* __restrict__ Wo2,
    const float* __restrict__ s_acc, const float* __restrict__ v_acc,
    float* __restrict__ g_all, float* __restrict__ out, int N)
{
    __shared__ float sWs[FDIM * FDIM], sWsT[FDIM * FDIM];
    __shared__ float sWo1[2 * FDIM * FDIM], sWo1T[2 * FDIM * FDIM];
    __shared__ float sb[FDIM], sW2o[FDIM], sTE[96];
    __shared__ float gred[8];
    for (int i = threadIdx.x; i < FDIM * FDIM; i += 256) {
        sWs[i] = Wself[i];
        sWsT[i] = Wself[(i & 31) * FDIM + (i >> 5)];
    }
    for (int i = threadIdx.x; i < 2 * FDIM * FDIM; i += 256) {
        sWo1[i] = Wo1[i];
        sWo1T[i] = Wo1[(i & 63) * FDIM + (i >> 6)];
    }
    for (int i = threadIdx.x; i < FDIM; i += 256) { sb[i] = bo1[i]; sW2o[i] = Wo2[i]; }
    for (int i = threadIdx.x; i < 96; i += 256) sTE[i] = temb[i];
    __syncthreads();

    const int lane = threadIdx.x & 31;
    const int g = threadIdx.x >> 5;
    float eAcc = 0.0f;

    for (int it = 0; it < 8; it++) {
        int a = blockIdx.x * 64 + it * 8 + g;
        const bool valid = (a < N);
        if (!valid) a = 0;

        float sv = s_acc[(size_t)a * FDIM + lane];
        float vx = v_acc[(size_t)a * 96 + 0 * 32 + lane];
        float vy = v_acc[(size_t)a * 96 + 1 * 32 + lane];
        float vz = v_acc[(size_t)a * 96 + 2 * 32 + lane];
        float h = sTE[types[a] * FDIM + lane];
        float vn = sqrtf(vx * vx + vy * vy + vz * vz + 1e-12f);

        float row = h;
        #pragma unroll
        for (int f = 0; f < FDIM; f++) {
            float t = __shfl(sv, f, 32);
            row += t * sWs[f * FDIM + lane];
        }
        float u = sb[lane];
        #pragma unroll
        for (int j = 0; j < FDIM; j++) {
            float rv = __shfl(row, j, 32);
            float vv = __shfl(vn, j, 32);
            u += rv * sWo1[j * FDIM + lane] + vv * sWo1[(j + FDIM) * FDIM + lane];
        }
        float sg = sigmoidf_(u);
        float au = u * sg;
        float pa = valid ? au * sW2o[lane] : 0.0f;
        #pragma unroll
        for (int m = 16; m; m >>= 1) pa += __shfl_xor(pa, m, 32);
        if (lane == 0) eAcc += pa;

        float gu = sW2o[lane] * (sg * (1.0f + u * (1.0f - sg)));
        float gfr = 0.0f, gfv = 0.0f;
        #pragma unroll
        for (int k = 0; k < FDIM; k++) {
            float gv_ = __shfl(gu, k, 32);
            gfr += gv_ * sWo1T[k * 64 + lane];
            gfv += gv_ * sWo1T[k * 64 + 32 + lane];
        }
        float gs = 0.0f;
        #pragma unroll
        for (int k = 0; k < FDIM; k++) {
            float gr = __shfl(gfr, k, 32);
            gs += gr * sWsT[k * FDIM + lane];
        }
        if (valid) {
            float sc = gfv / vn;
            *(float4*)&g_all[(size_t)a * 128 + lane * 4] =
                make_float4(gs, sc * vx, sc * vy, sc * vz);
        }
    }
    if (lane == 0) gred[g] = eAcc;
    __syncthreads();
    if (threadIdx.x == 0) {
        float t = 0.0f;
        #pragma unroll
        for (int i = 0; i < 8; i++) t += gred[i];
        unsafeAtomicAdd(out, t * EV2KJ_C);
    }
}

// ---------------- edge backward: single tile/wave; DS-strided D-stage ----------------
// src-side forces now go to fbuf (coalesced float4 per edge, dst-order); only dst-run
// leader atomics remain.
__global__ __launch_bounds__(256) void edge_bwd_mfma(
    const float* __restrict__ pos, const int* __restrict__ types,
    const int2* __restrict__ order_sd,
    const _Float16* __restrict__ wpack, const float* __restrict__ br1,
    const float* __restrict__ temb,
    const float* __restrict__ g_all,
    float* __restrict__ forces, float4* __restrict__ fbuf, int E)
{
    __shared__ __align__(16) _Float16 sR1[4][1280];
    __shared__ __align__(16) _Float16 sR2[4][1152];
    __shared__ int   sTy[4][16];
    __shared__ float sTemb[96];

    const int lane = threadIdx.x & 63;
    const int l16 = lane & 15;
    const int w = threadIdx.x >> 6;
    const int gbase = blockIdx.x * 64 + w * 16;

    for (int i = threadIdx.x; i < 96; i += 256) sTemb[i] = temb[i];
    __syncthreads();

    const int kb = (lane >> 4) * 8;
    // vector-load prepacked B fragments (8 x 16B, coalesced, L2-resident)
    const f16x8* wp = (const f16x8*)(wpack + (size_t)lane * 64);
    f16x8 bz[2] = { wp[0], wp[1] };
    f16x8 bf[4] = { wp[2], wp[3], wp[4], wp[5] };
    f16x8 bt[2] = { wp[6], wp[7] };

    // ---- phase 0: edge descriptors for ALL lanes (4 lanes mirror each edge) ----
    const int p_e = gbase + l16;
    const bool valid = (p_e < E);
    int2 sd = valid ? order_sd[p_e] : make_int2(0, 0);
    const int srcI = sd.x, dstI = sd.y;
    const int key = valid ? sd.y : (-2 - l16);

    float rinv = 1.f, env = 0.f, denv = 0.f, rhx = 0.f, rhy = 0.f, rhz = 0.f;
    if (lane < 16) {
        float rx = (pos[sd.y * 3 + 0] - pos[sd.x * 3 + 0]) * NM2A_C;
        float ry = (pos[sd.y * 3 + 1] - pos[sd.x * 3 + 1]) * NM2A_C;
        float rz = (pos[sd.y * 3 + 2] - pos[sd.x * 3 + 2]) * NM2A_C;
        float r2 = rx * rx + ry * ry + rz * rz + 1e-12f;
        float r = sqrtf(r2);
        rinv = 1.0f / r;
        float x = r * (1.0f / RCUT_C);
        float x2 = x * x, x4 = x2 * x2, x5 = x4 * x, x6 = x4 * x2, x7 = x6 * x, x8 = x6 * x2;
        env = (x < 1.0f) ? (1.0f - 28.0f * x6 + 48.0f * x7 - 21.0f * x8) : 0.0f;
        denv = (x < 1.0f) ? (-168.0f * x5 + 336.0f * x6 - 168.0f * x7) * (1.0f / RCUT_C) : 0.0f;
        rhx = rx * rinv; rhy = ry * rinv; rhz = rz * rinv;

        float th = PI_F * x, s1, c1;
        __sincosf(th, &s1, &c1);
        float sp = 0.0f, sn = s1, cp = 1.0f, cn = c1;
        _Float16 av[16];
        #pragma unroll
        for (int n = 0; n < NBASIS; n++) {
            float basis = sn * rinv;
            float dbdr = (PI_F * (float)(n + 1) * (1.0f / RCUT_C)) * cn * rinv - basis * rinv;
            av[n] = (_Float16)basis;
            av[8 + n] = (_Float16)dbdr;
            float snx = 2.0f * c1 * sn - sp; sp = sn; sn = snx;
            float cnx = 2.0f * c1 * cn - cp; cp = cn; cn = cnx;
        }
        _Float16* dstA = &sR1[w][l16 * QP];
        *(f16x8*)&dstA[0] = *(f16x8*)&av[0];
        *(f16x8*)&dstA[8] = *(f16x8*)&av[8];
        *(float4*)&dstA[16] = make_float4(0.f, 0.f, 0.f, 0.f);
        *(float4*)&dstA[24] = make_float4(0.f, 0.f, 0.f, 0.f);
        sTy[w][l16] = types[sd.x];
    }

    // ---- phase 1: 4 MFMAs (z, tacc over 2 ch-tiles); silu/tf -> Q (sR2) / T (sR1 upper) ----
    {
        const int me = lane & 15;
        f16x8 a1 = *(const f16x8*)&sR1[w][me * QP + kb];
        const f32x4 z4 = {0.f, 0.f, 0.f, 0.f};
        f32x4 Dz0 = __builtin_amdgcn_mfma_f32_16x16x32_f16(a1, bz[0], z4, 0, 0, 0);
        f32x4 Dz1 = __builtin_amdgcn_mfma_f32_16x16x32_f16(a1, bz[1], z4, 0, 0, 0);
        f32x4 Dt0 = __builtin_amdgcn_mfma_f32_16x16x32_f16(a1, bt[0], z4, 0, 0, 0);
        f32x4 Dt1 = __builtin_amdgcn_mfma_f32_16x16x32_f16(a1, bt[1], z4, 0, 0, 0);
        const int f0 = lane & 15, e0 = (lane >> 4) * 4;
        const float bb0 = br1[f0], bb1 = br1[16 + f0];
        #pragma unroll
        for (int t = 0; t < 2; t++) {
            f32x4 Dz = t ? Dz1 : Dz0;
            f32x4 Dt = t ? Dt1 : Dt0;
            float bb = t ? bb1 : bb0;
            #pragma unroll
            for (int r = 0; r < 4; r++) {
                float z = Dz[r] + bb;
                float sg = sigmoidf_(z);
                sR2[w][(e0 + r) * QP + t * 16 + f0] = (_Float16)(z * sg);
                sR1[w][640 + (e0 + r) * QP + t * 16 + f0] =
                    (_Float16)((sg * (1.0f + z * (1.0f - sg))) * Dt[r]);
            }
        }
    }

    // ---- phase 2: 8 MFMAs; fold hs; pack (x, x+32) channel pairs; DS-strided stores ----
    {
        const int me = lane & 15;
        f16x8 aq = *(const f16x8*)&sR2[w][me * QP + kb];
        f16x8 at = *(const f16x8*)&sR1[w][640 + me * QP + kb];
        const int cb = lane & 15, e0 = (lane >> 4) * 4;
        float hsv[2][4];   // [fpair][r]
        #pragma unroll
        for (int r = 0; r < 4; r++) {
            int ty = sTy[w][e0 + r];
            hsv[0][r] = sTemb[ty * 32 + cb];
            hsv[1][r] = sTemb[ty * 32 + 16 + cb];
        }
        const f32x4 z4 = {0.f, 0.f, 0.f, 0.f};
        unsigned int* DqU = (unsigned int*)&sR1[w][0];
        unsigned int* DtU = (unsigned int*)&sR2[w][0];
        #pragma unroll
        for (int fp = 0; fp < 2; fp++) {
            f32x4 q0 = __builtin_amdgcn_mfma_f32_16x16x32_f16(aq, bf[fp],     z4, 0, 0, 0);
            f32x4 q1 = __builtin_amdgcn_mfma_f32_16x16x32_f16(aq, bf[fp + 2], z4, 0, 0, 0);
            f32x4 t0 = __builtin_amdgcn_mfma_f32_16x16x32_f16(at, bf[fp],     z4, 0, 0, 0);
            f32x4 t1 = __builtin_amdgcn_mfma_f32_16x16x32_f16(at, bf[fp + 2], z4, 0, 0, 0);
            unsigned int pq[4], pt[4];
            #pragma unroll
            for (int r = 0; r < 4; r++) {
                float h = hsv[fp][r];
                pq[r] = pk2_(q0[r] * h, q1[r] * h);
                pt[r] = pk2_(t0[r] * h, t1[r] * h);
            }
            const int f = fp * 16 + cb;
            *(uint2*)&DqU[f * DS + e0]     = make_uint2(pq[0], pq[1]);
            *(uint2*)&DqU[f * DS + e0 + 2] = make_uint2(pq[2], pq[3]);
            *(uint2*)&DtU[f * DS + e0]     = make_uint2(pt[0], pt[1]);
            *(uint2*)&DtU[f * DS + e0 + 2] = make_uint2(pt[2], pt[3]);
        }
    }

    // ---- phase 3: epilogue; 4 lanes per edge (f split in 4), 2-step reduce ----
    {
        const unsigned int* DqU = (const unsigned int*)&sR1[w][0];
        const unsigned int* DtU = (const unsigned int*)&sR2[w][0];
        const int fb = (lane >> 4) * 8;     // f-group: 0..7, 8..15, 16..23, 24..31
        const float* gb = g_all + (size_t)dstI * 128;
        float Aa = 0.f, Bb = 0.f, Cc = 0.f, Pp = 0.f;
        float Ap = 0.f, Bp = 0.f, Cp = 0.f, Qq = 0.f;
        #pragma unroll
        for (int ff = 0; ff < 8; ff++) {
            const int f = fb + ff;
            unsigned int qp = DqU[f * DS + l16];
            unsigned int tp = DtU[f * DS + l16];
            float rw0 = lo16_(qp), rw1 = hi16_(qp);
            float u0 = lo16_(tp), u1 = hi16_(tp);
            float4 g4 = *(const float4*)(gb + f * 4);
            Pp += rw0 * g4.x; Qq += u0 * g4.x;
            Aa += rw1 * g4.y; Bb += rw1 * g4.z; Cc += rw1 * g4.w;
            Ap += u1 * g4.y;  Bp += u1 * g4.z;  Cp += u1 * g4.w;
        }
        // reduce across the 4 f-groups (lane bits 4 and 5)
        Pp += __shfl_xor(Pp, 16, 64); Qq += __shfl_xor(Qq, 16, 64);
        Aa += __shfl_xor(Aa, 16, 64); Bb += __shfl_xor(Bb, 16, 64);
        Cc += __shfl_xor(Cc, 16, 64); Ap += __shfl_xor(Ap, 16, 64);
        Bp += __shfl_xor(Bp, 16, 64); Cp += __shfl_xor(Cp, 16, 64);
        Pp += __shfl_xor(Pp, 32, 64); Qq += __shfl_xor(Qq, 32, 64);
        Aa += __shfl_xor(Aa, 32, 64); Bb += __shfl_xor(Bb, 32, 64);
        Cc += __shfl_xor(Cc, 32, 64); Ap += __shfl_xor(Ap, 32, 64);
        Bp += __shfl_xor(Bp, 32, 64); Cp += __shfl_xor(Cp, 32, 64);

        if (lane < 16) {
            float Gx = env * Aa, Gy = env * Bb, Gz = env * Cc;
            float genv = Pp + rhx * Aa + rhy * Bb + rhz * Cc;
            float pc = env * (Qq + rhx * Ap + rhy * Bp + rhz * Cp) + genv * denv;
            float dotg = Gx * rhx + Gy * rhy + Gz * rhz;
            float cx = pc * rhx + (Gx - dotg * rhx) * rinv;
            float cy = pc * rhy + (Gy - dotg * rhy) * rinv;
            float cz = pc * rhz + (Gz - dotg * rhz) * rinv;

            const float SC = EV2KJ_C * NM2A_C;
            // src-side: coalesced per-edge force record (dst-order position)
            if (valid) fbuf[p_e] = make_float4(SC * cx, SC * cy, SC * cz, 0.0f);

            // segmented inclusive scan over contiguous dst runs (16 edges)
            int kk = key;
            #pragma unroll
            for (int d = 1; d < 16; d <<= 1) {
                float ux = __shfl_up(cx, d, 32);
                float uy = __shfl_up(cy, d, 32);
                float uz = __shfl_up(cz, d, 32);
                int uk = __shfl_up(kk, d, 32);
                if (l16 >= d && uk == kk) { cx += ux; cy += uy; cz += uz; }
            }
            int nk = __shfl_down(kk, 1, 32);
            bool leader = (l16 == 15) || (nk != kk);
            if (valid && leader) {
                unsafeAtomicAdd(&forces[(size_t)dstI * 3 + 0], -SC * cx);
                unsafeAtomicAdd(&forces[(size_t)dstI * 3 + 1], -SC * cy);
                unsafeAtomicAdd(&forces[(size_t)dstI * 3 + 2], -SC * cz);
            }
        }
    }
}

// ------- src gather + net-force/mass reduction (replaces reduce_net) -------
// One thread per atom: sum this atom's src-side per-edge forces from fbuf via epos,
// add into forces (single writer per atom; dst-side atomics already landed),
// and accumulate net force + mass for the correction.
__global__ __launch_bounds__(256) void gather_reduce(
    float* __restrict__ f, const float* __restrict__ masses,
    const int* __restrict__ cursor, const int* __restrict__ epos,
    const float4* __restrict__ fbuf, float* __restrict__ accum,
    int N, int E)
{
    float nx = 0, ny = 0, nz = 0, ms = 0;
    for (int a = blockIdx.x * 256 + threadIdx.x; a < N; a += gridDim.x * 256) {
        int st = (a ? cursor[N + a - 1] : E) - E;
        int en = cursor[N + a] - E;
        float sx = 0.f, sy = 0.f, sz = 0.f;
        for (int j = st; j < en; j++) {
            float4 c = fbuf[epos[j]];
            sx += c.x; sy += c.y; sz += c.z;
        }
        float fx = f[a * 3 + 0] + sx;
        float fy = f[a * 3 + 1] + sy;
        float fz = f[a * 3 + 2] + sz;
        f[a * 3 + 0] = fx;
        f[a * 3 + 1] = fy;
        f[a * 3 + 2] = fz;
        nx += fx; ny += fy; nz += fz; ms += masses[a];
    }
    #pragma unroll
    for (int m = 32; m; m >>= 1) {
        nx += __shfl_xor(nx, m, 64);
        ny += __shfl_xor(ny, m, 64);
        nz += __shfl_xor(nz, m, 64);
        ms += __shfl_xor(ms, m, 64);
    }
    __shared__ float red[4][4];
    int w = threadIdx.x >> 6;
    if ((threadIdx.x & 63) == 0) { red[w][0] = nx; red[w][1] = ny; red[w][2] = nz; red[w][3] = ms; }
    __syncthreads();
    if (threadIdx.x == 0) {
        float a0 = 0, a1 = 0, a2 = 0, a3 = 0;
        for (int i = 0; i < 4; i++) { a0 += red[i][0]; a1 += red[i][1]; a2 += red[i][2]; a3 += red[i][3]; }
        unsafeAtomicAdd(accum + 0, a0);
        unsafeAtomicAdd(accum + 1, a1);
        unsafeAtomicAdd(accum + 2, a2);
        unsafeAtomicAdd(accum + 3, a3);
    }
}

__global__ __launch_bounds__(256) void correct_forces(
    float* __restrict__ f, const float* __restrict__ masses,
    const float* __restrict__ accum, int N)
{
    int i = blockIdx.x * 256 + threadIdx.x;
    if (i < N) {
        float c = masses[i] / accum[3];
        f[i * 3 + 0] -= c * accum[0];
        f[i * 3 + 1] -= c * accum[1];
        f[i * 3 + 2] -= c * accum[2];
    }
}

extern "C" void kernel_launch(void* const* d_in, const int* in_sizes, int n_in,
                              void* d_out, int out_size, void* d_ws, size_t ws_size,
                              hipStream_t stream)
{
    (void)n_in; (void)ws_size;
    const float* pos    = (const float*)d_in[0];
    const float* masses = (const float*)d_in[1];
    const float* temb   = (const float*)d_in[2];
    const float* Wr1    = (const float*)d_in[3];
    const float* br1    = (const float*)d_in[4];
    const float* Wr2    = (const float*)d_in[5];
    const float* Wself  = (const float*)d_in[6];
    const float* Wo1    = (const float*)d_in[7];
    const float* bo1    = (const float*)d_in[8];
    const float* Wo2    = (const float*)d_in[9];
    const int* types    = (const int*)d_in[10];
    const int* eidx     = (const int*)d_in[11];
    const int N = in_sizes[1];
    const int E = in_sizes[11] / 2;

    float* out = (float*)d_out;
    float* forces = out + 1;

    float* ws = (float*)d_ws;
    float* s_acc = ws;                               // N*32
    float* v_acc = s_acc + (size_t)N * FDIM;         // N*96
    float* g_all = v_acc + (size_t)N * 96;           // N*128 (packed gradients)
    float* accum = g_all + (size_t)N * 128;          // 4
    int* counts = (int*)(accum + 4);                 // 2N (dst | src)
    int* cursor = counts + 2 * (size_t)N;            // 2N
    int2* order_sd = (int2*)(cursor + 2 * (size_t)N);// E int2
    int* epos = (int*)(order_sd + E);                // E
    int NN = 2 * N;
    int nScan = (NN + SCH - 1) / SCH;
    int* bsum = epos + E;                            // nScan
    uintptr_t fb_addr = ((uintptr_t)(bsum + nScan) + 15) & ~(uintptr_t)15;
    float4* fbuf = (float4*)fb_addr;                 // E float4

    // per-lane MFMA B-fragment table (8 KB), overlaid on counts (dead after scan_write)
    uintptr_t wp_addr = ((uintptr_t)counts + 15) & ~(uintptr_t)15;
    _Float16* wpack = (_Float16*)wp_addr;

    hipMemsetAsync(d_out, 0, (size_t)out_size * sizeof(float), stream);
    hipMemsetAsync(s_acc, 0, (size_t)N * 128 * sizeof(float), stream);
    hipMemsetAsync(counts, 0, (size_t)NN * sizeof(int), stream);
    hipMemsetAsync(accum, 0, 4 * sizeof(float), stream);

    hist_dst<<<2048, 256, 0, stream>>>(eidx, counts, E, N);
    scan_partial<<<nScan, 256, 0, stream>>>(counts, bsum, NN);
    scan_bsum<<<1, 64, 0, stream>>>(bsum, nScan);
    scan_write<<<nScan, 256, 0, stream>>>(counts, bsum, cursor, NN);
    scatter_edges<<<2048, 256, 0, stream>>>(eidx, cursor, order_sd, epos, E, N);
    pack_wfrag<<<1, 64, 0, stream>>>(Wr1, Wr2, wpack);   // counts dead from here

    int nAtomBlocks = (N + 63) / 64;
    int nFwdBlocks = (E + 127) / 128;
    int nBwdBlocks = (E + 63) / 64;
    edge_fwd_mfma<<<nFwdBlocks, 256, 0, stream>>>(pos, types, order_sd,
                                                  wpack, br1, temb,
                                                  s_acc, v_acc, E);
    atom_mlp<<<nAtomBlocks, 256, 0, stream>>>(types, temb, Wself, Wo1, bo1, Wo2,
                                              s_acc, v_acc, g_all, out, N);
    edge_bwd_mfma<<<nBwdBlocks, 256, 0, stream>>>(pos, types, order_sd,
                                                  wpack, br1, temb,
                                                  g_all, forces, fbuf, E);
    gather_reduce<<<256, 256, 0, stream>>>(forces, masses, cursor, epos, fbuf,
                                           accum, N, E);
    correct_forces<<<(N + 255) / 256, 256, 0, stream>>>(forces, masses, accum, N);
}

// Round 3
// 454.806 us; speedup vs baseline: 1.3102x; 1.3102x over previous
//
#include <hip/hip_runtime.h>
#include <math.h>

#define FDIM 32
#define NBASIS 8
#define QP 40     // A-stage row pad (f16 units) -> 80B rows, 16B-aligned quads
#define DS 18     // bwd D-stage stride (uints): (8*DS)%32=16 -> 2-way bank aliasing (free)
#define BINW 4096 // edges per bin_dst window
#define DCAP 4096 // sort_bucket LDS record capacity
#define GSPLIT 8  // gather WGs per src bucket

constexpr float RCUT_C = 20.0f;
constexpr float PI_F = 3.14159265358979323846f;
constexpr float EV2KJ_C = 96.4853f;
constexpr float NM2A_C = 10.0f;

typedef _Float16 f16x8 __attribute__((ext_vector_type(8)));
typedef _Float16 f16x4 __attribute__((ext_vector_type(4)));
typedef float f32x4 __attribute__((ext_vector_type(4)));

__device__ __forceinline__ float sigmoidf_(float z) { return 1.0f / (1.0f + __expf(-z)); }

__device__ __forceinline__ unsigned int pk2_(float a, float b) {
    unsigned short lo = __builtin_bit_cast(unsigned short, (_Float16)a);
    unsigned short hi = __builtin_bit_cast(unsigned short, (_Float16)b);
    return (unsigned int)lo | ((unsigned int)hi << 16);
}
__device__ __forceinline__ float lo16_(unsigned int v) {
    return (float)__builtin_bit_cast(_Float16, (unsigned short)(v & 0xffffu));
}
__device__ __forceinline__ float hi16_(unsigned int v) {
    return (float)__builtin_bit_cast(_Float16, (unsigned short)(v >> 16));
}

// ---------------- bucketed CSR build (no N-wide scans, no random scatter) ----------------
// K1: LDS-aggregated bucket histograms (dst buckets <=512, src buckets <=64)
__global__ __launch_bounds__(256) void hist_buckets(
    const int* __restrict__ eidx, int* __restrict__ dbcnt, int* __restrict__ sbcnt,
    int E, int dsh, int ssh, int nbd, int nbs)
{
    __shared__ int ld[512];
    __shared__ int ls[64];
    for (int i = threadIdx.x; i < nbd; i += 256) ld[i] = 0;
    for (int i = threadIdx.x; i < nbs; i += 256) ls[i] = 0;
    __syncthreads();
    for (int e = blockIdx.x * 256 + threadIdx.x; e < E; e += gridDim.x * 256) {
        int s = eidx[e];
        int d = eidx[E + e];
        atomicAdd(&ld[d >> dsh], 1);
        atomicAdd(&ls[s >> ssh], 1);
    }
    __syncthreads();
    for (int i = threadIdx.x; i < nbd; i += 256) if (ld[i]) atomicAdd(&dbcnt[i], ld[i]);
    for (int i = threadIdx.x; i < nbs; i += 256) if (ls[i]) atomicAdd(&sbcnt[i], ls[i]);
}

// K2: block-parallel exclusive scans of both bucket-count arrays
__global__ __launch_bounds__(512) void scan_bases(
    const int* __restrict__ dbcnt, const int* __restrict__ sbcnt,
    int* __restrict__ dbbase, int* __restrict__ sbbase, int nbd, int nbs)
{
    __shared__ int buf[512];
    const int t = threadIdx.x;
    int v = (t < nbd) ? dbcnt[t] : 0;
    buf[t] = v;
    __syncthreads();
    for (int off = 1; off < 512; off <<= 1) {
        int u = (t >= off) ? buf[t - off] : 0;
        __syncthreads();
        buf[t] += u;
        __syncthreads();
    }
    if (t < nbd) dbbase[t] = buf[t] - v;
    if (t == 511) dbbase[nbd] = buf[511];
    __syncthreads();
    int v2 = (t < nbs) ? sbcnt[t] : 0;
    buf[t] = v2;
    __syncthreads();
    for (int off = 1; off < 512; off <<= 1) {
        int u = (t >= off) ? buf[t - off] : 0;
        __syncthreads();
        buf[t] += u;
        __syncthreads();
    }
    if (t < nbs) sbbase[t] = buf[t] - v2;
    if (t == 511) sbbase[nbs] = buf[511];
}

// K3: partition edges into dst-bucket regions of order_sd (unsorted within bucket).
// Per-window LDS staging + per-bucket chunk reservation -> line-dense writes.
__global__ __launch_bounds__(256) void bin_dst(
    const int* __restrict__ eidx, const int* __restrict__ dbbase,
    int* __restrict__ dbcur, int2* __restrict__ order_sd,
    int E, int dsh, int nbd)
{
    __shared__ int2 rec[BINW];          // 32 KB
    __shared__ int lcnt[512], lbase[512], lofs[512];
    const int t = threadIdx.x;
    const int w0 = blockIdx.x * BINW;
    const int n = min(BINW, E - w0);
    if (n <= 0) return;
    for (int i = t; i < nbd; i += 256) lcnt[i] = 0;
    __syncthreads();
    for (int i = t; i < n; i += 256) {
        int e = w0 + i;
        int2 r = make_int2(eidx[e], eidx[E + e]);
        rec[i] = r;
        atomicAdd(&lcnt[r.y >> dsh], 1);
    }
    __syncthreads();
    for (int i = t; i < nbd; i += 256) {
        int c = lcnt[i];
        lbase[i] = c ? atomicAdd(&dbcur[i], c) : 0;
        lofs[i] = 0;
    }
    __syncthreads();
    for (int i = t; i < n; i += 256) {
        int2 r = rec[i];
        int b = r.y >> dsh;
        int pos = lbase[b] + atomicAdd(&lofs[b], 1);
        order_sd[dbbase[b] + pos] = r;
    }
}

// K4: per-bucket LDS counting sort (in place); emits (src, p) into src-bins with
// per-bucket chunk reservations. Sorting is perf-only; chunked fallback stays correct.
__global__ __launch_bounds__(256) void sort_bucket(
    int2* __restrict__ order_sd, const int* __restrict__ dbbase,
    int* __restrict__ sbcur, const int* __restrict__ sbbase,
    int2* __restrict__ srcbin, int dsh, int ssh)
{
    __shared__ int2 rec[DCAP];          // 32 KB
    __shared__ int c128[128], o128[128];
    __shared__ int sc[64], sbres[64], so[64];
    const int b = blockIdx.x, t = threadIdx.x;
    const int base = dbbase[b];
    const int cnt = dbbase[b + 1] - base;
    const bool dosort = (dsh <= 7);
    const int kmask = (1 << dsh) - 1;

    for (int start = 0; start < cnt; start += DCAP) {
        const int n = min(DCAP, cnt - start);
        if (t < 128) c128[t] = 0;
        if (t < 64) sc[t] = 0;
        __syncthreads();
        for (int i = t; i < n; i += 256) {
            int2 r = order_sd[base + start + i];
            rec[i] = r;
            if (dosort) atomicAdd(&c128[r.y & kmask], 1);
            atomicAdd(&sc[r.x >> ssh], 1);
        }
        __syncthreads();
        // exclusive scan of c128 (Hillis-Steele, full-block barriers)
        int v0 = (t < 128) ? c128[t] : 0;
        __syncthreads();
        for (int off = 1; off < 128; off <<= 1) {
            int u = (t < 128 && t >= off) ? c128[t - off] : 0;
            __syncthreads();
            if (t < 128) c128[t] += u;
            __syncthreads();
        }
        if (t < 128) o128[t] = c128[t] - v0;
        // reserve src-bin chunks
        if (t < 64) {
            int c = sc[t];
            sbres[t] = c ? atomicAdd(&sbcur[t], c) : 0;
            so[t] = 0;
        }
        __syncthreads();
        for (int i = t; i < n; i += 256) {
            int2 r = rec[i];
            int p;
            if (dosort) {
                int pos = atomicAdd(&o128[r.y & kmask], 1);
                p = base + start + pos;
                order_sd[p] = r;
            } else {
                p = base + start + i;   // no reorder (fallback)
            }
            int sb2 = r.x >> ssh;
            int slot = sbres[sb2] + atomicAdd(&so[sb2], 1);
            srcbin[sbbase[sb2] + slot] = make_int2(r.x, p);
        }
        __syncthreads();
    }
}

// ---------------- weight fragment pre-pack: per-lane MFMA B operands ----------------
// Layout per lane (64 f16 = 128B): [0:8)=bz0 [8:16)=bz1 [16:24)=bf0 [24:32)=bf1
//                                  [32:40)=bf2 [40:48)=bf3 [48:56)=bt0 [56:64)=bt1
__global__ __launch_bounds__(64) void pack_wfrag(
    const float* __restrict__ Wr1, const float* __restrict__ Wr2,
    _Float16* __restrict__ wpack)
{
    const int lane = threadIdx.x;          // 0..63
    const int kb = (lane >> 4) * 8, nb = lane & 15;
    _Float16* o = wpack + (size_t)lane * 64;
    #pragma unroll
    for (int t = 0; t < 2; t++)
        #pragma unroll
        for (int j = 0; j < 8; j++) {
            int k = kb + j;
            o[t * 8 + j] = (k < 8) ? (_Float16)Wr1[k * FDIM + t * 16 + nb] : (_Float16)0.0f;
        }
    #pragma unroll
    for (int t = 0; t < 4; t++)
        #pragma unroll
        for (int j = 0; j < 8; j++)
            o[16 + t * 8 + j] = (_Float16)Wr2[(kb + j) * 64 + t * 16 + nb];
    #pragma unroll
    for (int t = 0; t < 2; t++)
        #pragma unroll
        for (int j = 0; j < 8; j++) {
            int k = kb + j;
            o[48 + t * 8 + j] = (k >= 8 && k < 16) ? (_Float16)Wr1[(k - 8) * FDIM + t * 16 + nb]
                                                   : (_Float16)0.0f;
        }
}

// ---------------- edge forward: hs*env folded into packed D; LDS-stashed keys ----------------
__global__ __launch_bounds__(256) void edge_fwd_mfma(
    const float* __restrict__ pos, const int* __restrict__ types,
    const int2* __restrict__ order_sd,
    const _Float16* __restrict__ wpack, const float* __restrict__ br1,
    const float* __restrict__ temb,
    float* __restrict__ s_acc, float* __restrict__ v_acc, int E)
{
    __shared__ __align__(16) _Float16 sR[4][2560];
    __shared__ float sSt[4][32][4];         // env, rhx, rhy, rhz
    __shared__ int sTy[4][32];
    __shared__ int sKey[4][32];
    __shared__ float sTemb[96];

    const int lane = threadIdx.x & 63;
    const int l32 = threadIdx.x & 31;
    const int hw = (threadIdx.x >> 5) & 1;
    const int w = threadIdx.x >> 6;
    const int gbase = blockIdx.x * 128 + w * 32;

    for (int i = threadIdx.x; i < 96; i += 256) sTemb[i] = temb[i];
    __syncthreads();

    const int kb = (lane >> 4) * 8;
    const f16x8* wp = (const f16x8*)(wpack + (size_t)lane * 64);
    f16x8 bz[2] = { wp[0], wp[1] };
    f16x8 bf[4] = { wp[2], wp[3], wp[4], wp[5] };

    // ---- phase 0: lane-parallel geometry + basis (lanes 0..31) ----
    if (lane < 32) {
        const int ed = l32;
        const int p = gbase + ed;
        const bool vld = (p < E);
        int2 sd = vld ? order_sd[p] : make_int2(0, 0);
        float rx = (pos[sd.y * 3 + 0] - pos[sd.x * 3 + 0]) * NM2A_C;
        float ry = (pos[sd.y * 3 + 1] - pos[sd.x * 3 + 1]) * NM2A_C;
        float rz = (pos[sd.y * 3 + 2] - pos[sd.x * 3 + 2]) * NM2A_C;
        float r2 = rx * rx + ry * ry + rz * rz + 1e-12f;
        float r = sqrtf(r2);
        float rinv = 1.0f / r;
        float x = r * (1.0f / RCUT_C);
        float x2 = x * x, x4 = x2 * x2, x6 = x4 * x2, x7 = x6 * x, x8 = x6 * x2;
        float env = (x < 1.0f) ? (1.0f - 28.0f * x6 + 48.0f * x7 - 21.0f * x8) : 0.0f;

        float th = PI_F * x, s1, c1;
        __sincosf(th, &s1, &c1);
        float sp = 0.0f, sn = s1;
        _Float16 av[8];
        #pragma unroll
        for (int n = 0; n < NBASIS; n++) {
            av[n] = (_Float16)(sn * rinv);
            float snx = 2.0f * c1 * sn - sp; sp = sn; sn = snx;
        }
        _Float16* dstA = &sR[w][(ed < 16 ? 0 : 640) + (ed & 15) * QP];
        *(f16x8*)&dstA[0] = *(f16x8*)&av[0];
        *(float4*)&dstA[8]  = make_float4(0.f, 0.f, 0.f, 0.f);
        *(float4*)&dstA[16] = make_float4(0.f, 0.f, 0.f, 0.f);
        *(float4*)&dstA[24] = make_float4(0.f, 0.f, 0.f, 0.f);
        sSt[w][ed][0] = env;
        sSt[w][ed][1] = rx * rinv;
        sSt[w][ed][2] = ry * rinv;
        sSt[w][ed][3] = rz * rinv;
        sTy[w][ed] = types[sd.x];
        sKey[w][ed] = vld ? sd.y : -1;
    }

    // ---- phase 1: MFMA basis layer -> z, silu -> Q (both tiles) ----
    {
        const int me = lane & 15;
        f16x8 a1a = *(const f16x8*)&sR[w][me * QP + kb];
        f16x8 a1b = *(const f16x8*)&sR[w][640 + me * QP + kb];
        const f32x4 z4 = {0.f, 0.f, 0.f, 0.f};
        f32x4 Dz0a = __builtin_amdgcn_mfma_f32_16x16x32_f16(a1a, bz[0], z4, 0, 0, 0);
        f32x4 Dz1a = __builtin_amdgcn_mfma_f32_16x16x32_f16(a1a, bz[1], z4, 0, 0, 0);
        f32x4 Dz0b = __builtin_amdgcn_mfma_f32_16x16x32_f16(a1b, bz[0], z4, 0, 0, 0);
        f32x4 Dz1b = __builtin_amdgcn_mfma_f32_16x16x32_f16(a1b, bz[1], z4, 0, 0, 0);
        const int f0 = lane & 15, e0 = (lane >> 4) * 4;
        const float bb0 = br1[f0], bb1 = br1[16 + f0];
        #pragma unroll
        for (int t = 0; t < 2; t++) {
            f32x4 Dza = t ? Dz1a : Dz0a;
            f32x4 Dzb = t ? Dz1b : Dz0b;
            float bb = t ? bb1 : bb0;
            #pragma unroll
            for (int r = 0; r < 4; r++) {
                float za = Dza[r] + bb;
                float zb = Dzb[r] + bb;
                sR[w][1280 + (e0 + r) * QP + t * 16 + f0] = (_Float16)(za * sigmoidf_(za));
                sR[w][1920 + (e0 + r) * QP + t * 16 + f0] = (_Float16)(zb * sigmoidf_(zb));
            }
        }
    }

    // ---- phase 2: MFMA W2; fold hs*env; pack (ch, ch+32) pairs; D[edge*32+ch] ----
    {
        const int me = lane & 15;
        f16x8 aqa = *(const f16x8*)&sR[w][1280 + me * QP + kb];
        f16x8 aqb = *(const f16x8*)&sR[w][1920 + me * QP + kb];
        const int cb = lane & 15, e0 = (lane >> 4) * 4;
        float hev[2][2][4];   // [tile][fpair][r] = hs(ch)*env
        #pragma unroll
        for (int tl = 0; tl < 2; tl++)
            #pragma unroll
            for (int fp = 0; fp < 2; fp++)
                #pragma unroll
                for (int r = 0; r < 4; r++) {
                    int ed = tl * 16 + e0 + r;
                    hev[tl][fp][r] = sTemb[sTy[w][ed] * 32 + fp * 16 + cb] * sSt[w][ed][0];
                }
        const f32x4 z4 = {0.f, 0.f, 0.f, 0.f};
        unsigned int* DU = (unsigned int*)&sR[w][0];
        #pragma unroll
        for (int fp = 0; fp < 2; fp++) {
            f32x4 a0 = __builtin_amdgcn_mfma_f32_16x16x32_f16(aqa, bf[fp],     z4, 0, 0, 0);
            f32x4 a1 = __builtin_amdgcn_mfma_f32_16x16x32_f16(aqa, bf[fp + 2], z4, 0, 0, 0);
            f32x4 b0 = __builtin_amdgcn_mfma_f32_16x16x32_f16(aqb, bf[fp],     z4, 0, 0, 0);
            f32x4 b1 = __builtin_amdgcn_mfma_f32_16x16x32_f16(aqb, bf[fp + 2], z4, 0, 0, 0);
            #pragma unroll
            for (int r = 0; r < 4; r++) {
                float ha = hev[0][fp][r], hb = hev[1][fp][r];
                DU[(e0 + r) * 32 + fp * 16 + cb]        = pk2_(a0[r] * ha, a1[r] * ha);
                DU[(16 + e0 + r) * 32 + fp * 16 + cb]   = pk2_(b0[r] * hb, b1[r] * hb);
            }
        }
    }

    // ---- phase 3: epilogue, run-merge carried across both tiles (keys from LDS) ----
    const unsigned int* DU = (const unsigned int*)&sR[w][0];
    int runKey = -1;
    float sAcc = 0.f, vXA = 0.f, vYA = 0.f, vZA = 0.f;
    #pragma unroll
    for (int t = 0; t < 2; t++) {
        #pragma unroll
        for (int i = 0; i < 8; i++) {
            const int m = t * 16 + hw * 8 + i;
            const int p = gbase + m;
            if (p >= E) break;
            int k = sKey[w][m];
            if (k != runKey) {
                if (runKey >= 0) {
                    unsafeAtomicAdd(&s_acc[(size_t)runKey * 32 + l32], sAcc);
                    unsafeAtomicAdd(&v_acc[(size_t)runKey * 96 + 0 * 32 + l32], vXA);
                    unsafeAtomicAdd(&v_acc[(size_t)runKey * 96 + 1 * 32 + l32], vYA);
                    unsafeAtomicAdd(&v_acc[(size_t)runKey * 96 + 2 * 32 + l32], vZA);
                }
                runKey = k;
                sAcc = vXA = vYA = vZA = 0.f;
            }
            unsigned int qp = DU[m * 32 + l32];
            float s0 = lo16_(qp);       // hs*env*rw0
            float h1 = hi16_(qp);       // hs*env*rw1
            sAcc += s0;
            vXA += h1 * sSt[w][m][1];
            vYA += h1 * sSt[w][m][2];
            vZA += h1 * sSt[w][m][3];
        }
    }
    if (runKey >= 0) {
        unsafeAtomicAdd(&s_acc[(size_t)runKey * 32 + l32], sAcc);
        unsafeAtomicAdd(&v_acc[(size_t)runKey * 96 + 0 * 32 + l32], vXA);
        unsafeAtomicAdd(&v_acc[(size_t)runKey * 96 + 1 * 32 + l32], vYA);
        unsafeAtomicAdd(&v_acc[(size_t)runKey * 96 + 2 * 32 + l32], vZA);
    }
}

// -------- atom MLP: 64 atoms/block; packed g_all writes; energy fused (atomic) --------
__global__ __launch_bounds__(256) void atom_mlp(
    const int* __restrict__ types, const float* __restrict__ temb,
    const float* __restrict__ Wself, const float* __restrict__ Wo1,
    const float* __restrict__ bo1, const float* __restrict__ Wo2,
    const float* __restrict__ s_acc, const float* __restrict__ v_acc,
    float* __restrict__ g_all, float* __restrict__ out, int N)
{
    __shared__ float sWs[FDIM * FDIM], sWsT[FDIM * FDIM];
    __shared__ float sWo1[2 * FDIM * FDIM], sWo1T[2 * FDIM * FDIM];
    __shared__ float sb[FDIM], sW2o[FDIM], sTE[96];
    __shared__ float gred[8];
    for (int i = threadIdx.x; i < FDIM * FDIM; i += 256) {
        sWs[i] = Wself[i];
        sWsT[i] = Wself[(i & 31) * FDIM + (i >> 5)];
    }
    for (int i = threadIdx.x; i < 2 * FDIM * FDIM; i += 256) {
        sWo1[i] = Wo1[i];
        sWo1T[i] = Wo1[(i & 63) * FDIM + (i >> 6)];
    }
    for (int i = threadIdx.x; i < FDIM; i += 256) { sb[i] = bo1[i]; sW2o[i] = Wo2[i]; }
    for (int i = threadIdx.x; i < 96; i += 256) sTE[i] = temb[i];
    __syncthreads();

    const int lane = threadIdx.x & 31;
    const int g = threadIdx.x >> 5;
    float eAcc = 0.0f;

    for (int it = 0; it < 8; it++) {
        int a = blockIdx.x * 64 + it * 8 + g;
        const bool valid = (a < N);
        if (!valid) a = 0;

        float sv = s_acc[(size_t)a * FDIM + lane];
        float vx = v_acc[(size_t)a * 96 + 0 * 32 + lane];
        float vy = v_acc[(size_t)a * 96 + 1 * 32 + lane];
        float vz = v_acc[(size_t)a * 96 + 2 * 32 + lane];
        float h = sTE[types[a] * FDIM + lane];
        float vn = sqrtf(vx * vx + vy * vy + vz * vz + 1e-12f);

        float row = h;
        #pragma unroll
        for (int f = 0; f < FDIM; f++) {
            float t = __shfl(sv, f, 32);
            row += t * sWs[f * FDIM + lane];
        }
        float u = sb[lane];
        #pragma unroll
        for (int j = 0; j < FDIM; j++) {
            float rv = __shfl(row, j, 32);
            float vv = __shfl(vn, j, 32);
            u += rv * sWo1[j * FDIM + lane] + vv * sWo1[(j + FDIM) * FDIM + lane];
        }
        float sg = sigmoidf_(u);
        float au = u * sg;
        float pa = valid ? au * sW2o[lane] : 0.0f;
        #pragma unroll
        for (int m = 16; m; m >>= 1) pa += __shfl_xor(pa, m, 32);
        if (lane == 0) eAcc += pa;

        float gu = sW2o[lane] * (sg * (1.0f + u * (1.0f - sg)));
        float gfr = 0.0f, gfv = 0.0f;
        #pragma unroll
        for (int k = 0; k < FDIM; k++) {
            float gv_ = __shfl(gu, k, 32);
            gfr += gv_ * sWo1T[k * 64 + lane];
            gfv += gv_ * sWo1T[k * 64 + 32 + lane];
        }
        float gs = 0.0f;
        #pragma unroll
        for (int k = 0; k < FDIM; k++) {
            float gr = __shfl(gfr, k, 32);
            gs += gr * sWsT[k * FDIM + lane];
        }
        if (valid) {
            float sc = gfv / vn;
            *(float4*)&g_all[(size_t)a * 128 + lane * 4] =
                make_float4(gs, sc * vx, sc * vy, sc * vz);
        }
    }
    if (lane == 0) gred[g] = eAcc;
    __syncthreads();
    if (threadIdx.x == 0) {
        float t = 0.0f;
        #pragma unroll
        for (int i = 0; i < 8; i++) t += gred[i];
        unsafeAtomicAdd(out, t * EV2KJ_C);
    }
}

// ---------------- edge backward: single tile/wave; DS-strided D-stage ----------------
// src-side forces go to fbuf (coalesced float4 per edge, dst-order); only dst-run
// leader atomics remain.
__global__ __launch_bounds__(256) void edge_bwd_mfma(
    const float* __restrict__ pos, const int* __restrict__ types,
    const int2* __restrict__ order_sd,
    const _Float16* __restrict__ wpack, const float* __restrict__ br1,
    const float* __restrict__ temb,
    const float* __restrict__ g_all,
    float* __restrict__ forces, float4* __restrict__ fbuf, int E)
{
    __shared__ __align__(16) _Float16 sR1[4][1280];
    __shared__ __align__(16) _Float16 sR2[4][1152];
    __shared__ int   sTy[4][16];
    __shared__ float sTemb[96];

    const int lane = threadIdx.x & 63;
    const int l16 = lane & 15;
    const int w = threadIdx.x >> 6;
    const int gbase = blockIdx.x * 64 + w * 16;

    for (int i = threadIdx.x; i < 96; i += 256) sTemb[i] = temb[i];
    __syncthreads();

    const int kb = (lane >> 4) * 8;
    const f16x8* wp = (const f16x8*)(wpack + (size_t)lane * 64);
    f16x8 bz[2] = { wp[0], wp[1] };
    f16x8 bf[4] = { wp[2], wp[3], wp[4], wp[5] };
    f16x8 bt[2] = { wp[6], wp[7] };

    // ---- phase 0: edge descriptors for ALL lanes (4 lanes mirror each edge) ----
    const int p_e = gbase + l16;
    const bool valid = (p_e < E);
    int2 sd = valid ? order_sd[p_e] : make_int2(0, 0);
    const int srcI = sd.x, dstI = sd.y;
    const int key = valid ? sd.y : (-2 - l16);
    (void)srcI;

    float rinv = 1.f, env = 0.f, denv = 0.f, rhx = 0.f, rhy = 0.f, rhz = 0.f;
    if (lane < 16) {
        float rx = (pos[sd.y * 3 + 0] - pos[sd.x * 3 + 0]) * NM2A_C;
        float ry = (pos[sd.y * 3 + 1] - pos[sd.x * 3 + 1]) * NM2A_C;
        float rz = (pos[sd.y * 3 + 2] - pos[sd.x * 3 + 2]) * NM2A_C;
        float r2 = rx * rx + ry * ry + rz * rz + 1e-12f;
        float r = sqrtf(r2);
        rinv = 1.0f / r;
        float x = r * (1.0f / RCUT_C);
        float x2 = x * x, x4 = x2 * x2, x5 = x4 * x, x6 = x4 * x2, x7 = x6 * x, x8 = x6 * x2;
        env = (x < 1.0f) ? (1.0f - 28.0f * x6 + 48.0f * x7 - 21.0f * x8) : 0.0f;
        denv = (x < 1.0f) ? (-168.0f * x5 + 336.0f * x6 - 168.0f * x7) * (1.0f / RCUT_C) : 0.0f;
        rhx = rx * rinv; rhy = ry * rinv; rhz = rz * rinv;

        float th = PI_F * x, s1, c1;
        __sincosf(th, &s1, &c1);
        float sp = 0.0f, sn = s1, cp = 1.0f, cn = c1;
        _Float16 av[16];
        #pragma unroll
        for (int n = 0; n < NBASIS; n++) {
            float basis = sn * rinv;
            float dbdr = (PI_F * (float)(n + 1) * (1.0f / RCUT_C)) * cn * rinv - basis * rinv;
            av[n] = (_Float16)basis;
            av[8 + n] = (_Float16)dbdr;
            float snx = 2.0f * c1 * sn - sp; sp = sn; sn = snx;
            float cnx = 2.0f * c1 * cn - cp; cp = cn; cn = cnx;
        }
        _Float16* dstA = &sR1[w][l16 * QP];
        *(f16x8*)&dstA[0] = *(f16x8*)&av[0];
        *(f16x8*)&dstA[8] = *(f16x8*)&av[8];
        *(float4*)&dstA[16] = make_float4(0.f, 0.f, 0.f, 0.f);
        *(float4*)&dstA[24] = make_float4(0.f, 0.f, 0.f, 0.f);
        sTy[w][l16] = types[sd.x];
    }

    // ---- phase 1: 4 MFMAs (z, tacc over 2 ch-tiles); silu/tf -> Q (sR2) / T (sR1 upper) ----
    {
        const int me = lane & 15;
        f16x8 a1 = *(const f16x8*)&sR1[w][me * QP + kb];
        const f32x4 z4 = {0.f, 0.f, 0.f, 0.f};
        f32x4 Dz0 = __builtin_amdgcn_mfma_f32_16x16x32_f16(a1, bz[0], z4, 0, 0, 0);
        f32x4 Dz1 = __builtin_amdgcn_mfma_f32_16x16x32_f16(a1, bz[1], z4, 0, 0, 0);
        f32x4 Dt0 = __builtin_amdgcn_mfma_f32_16x16x32_f16(a1, bt[0], z4, 0, 0, 0);
        f32x4 Dt1 = __builtin_amdgcn_mfma_f32_16x16x32_f16(a1, bt[1], z4, 0, 0, 0);
        const int f0 = lane & 15, e0 = (lane >> 4) * 4;
        const float bb0 = br1[f0], bb1 = br1[16 + f0];
        #pragma unroll
        for (int t = 0; t < 2; t++) {
            f32x4 Dz = t ? Dz1 : Dz0;
            f32x4 Dt = t ? Dt1 : Dt0;
            float bb = t ? bb1 : bb0;
            #pragma unroll
            for (int r = 0; r < 4; r++) {
                float z = Dz[r] + bb;
                float sg = sigmoidf_(z);
                sR2[w][(e0 + r) * QP + t * 16 + f0] = (_Float16)(z * sg);
                sR1[w][640 + (e0 + r) * QP + t * 16 + f0] =
                    (_Float16)((sg * (1.0f + z * (1.0f - sg))) * Dt[r]);
            }
        }
    }

    // ---- phase 2: 8 MFMAs; fold hs; pack (x, x+32) channel pairs; DS-strided stores ----
    {
        const int me = lane & 15;
        f16x8 aq = *(const f16x8*)&sR2[w][me * QP + kb];
        f16x8 at = *(const f16x8*)&sR1[w][640 + me * QP + kb];
        const int cb = lane & 15, e0 = (lane >> 4) * 4;
        float hsv[2][4];   // [fpair][r]
        #pragma unroll
        for (int r = 0; r < 4; r++) {
            int ty = sTy[w][e0 + r];
            hsv[0][r] = sTemb[ty * 32 + cb];
            hsv[1][r] = sTemb[ty * 32 + 16 + cb];
        }
        const f32x4 z4 = {0.f, 0.f, 0.f, 0.f};
        unsigned int* DqU = (unsigned int*)&sR1[w][0];
        unsigned int* DtU = (unsigned int*)&sR2[w][0];
        #pragma unroll
        for (int fp = 0; fp < 2; fp++) {
            f32x4 q0 = __builtin_amdgcn_mfma_f32_16x16x32_f16(aq, bf[fp],     z4, 0, 0, 0);
            f32x4 q1 = __builtin_amdgcn_mfma_f32_16x16x32_f16(aq, bf[fp + 2], z4, 0, 0, 0);
            f32x4 t0 = __builtin_amdgcn_mfma_f32_16x16x32_f16(at, bf[fp],     z4, 0, 0, 0);
            f32x4 t1 = __builtin_amdgcn_mfma_f32_16x16x32_f16(at, bf[fp + 2], z4, 0, 0, 0);
            unsigned int pq[4], pt[4];
            #pragma unroll
            for (int r = 0; r < 4; r++) {
                float h = hsv[fp][r];
                pq[r] = pk2_(q0[r] * h, q1[r] * h);
                pt[r] = pk2_(t0[r] * h, t1[r] * h);
            }
            const int f = fp * 16 + cb;
            *(uint2*)&DqU[f * DS + e0]     = make_uint2(pq[0], pq[1]);
            *(uint2*)&DqU[f * DS + e0 + 2] = make_uint2(pq[2], pq[3]);
            *(uint2*)&DtU[f * DS + e0]     = make_uint2(pt[0], pt[1]);
            *(uint2*)&DtU[f * DS + e0 + 2] = make_uint2(pt[2], pt[3]);
        }
    }

    // ---- phase 3: epilogue; 4 lanes per edge (f split in 4), 2-step reduce ----
    {
        const unsigned int* DqU = (const unsigned int*)&sR1[w][0];
        const unsigned int* DtU = (const unsigned int*)&sR2[w][0];
        const int fb = (lane >> 4) * 8;     // f-group: 0..7, 8..15, 16..23, 24..31
        const float* gb = g_all + (size_t)dstI * 128;
        float Aa = 0.f, Bb = 0.f, Cc = 0.f, Pp = 0.f;
        float Ap = 0.f, Bp = 0.f, Cp = 0.f, Qq = 0.f;
        #pragma unroll
        for (int ff = 0; ff < 8; ff++) {
            const int f = fb + ff;
            unsigned int qp = DqU[f * DS + l16];
            unsigned int tp = DtU[f * DS + l16];
            float rw0 = lo16_(qp), rw1 = hi16_(qp);
            float u0 = lo16_(tp), u1 = hi16_(tp);
            float4 g4 = *(const float4*)(gb + f * 4);
            Pp += rw0 * g4.x; Qq += u0 * g4.x;
            Aa += rw1 * g4.y; Bb += rw1 * g4.z; Cc += rw1 * g4.w;
            Ap += u1 * g4.y;  Bp += u1 * g4.z;  Cp += u1 * g4.w;
        }
        // reduce across the 4 f-groups (lane bits 4 and 5)
        Pp += __shfl_xor(Pp, 16, 64); Qq += __shfl_xor(Qq, 16, 64);
        Aa += __shfl_xor(Aa, 16, 64); Bb += __shfl_xor(Bb, 16, 64);
        Cc += __shfl_xor(Cc, 16, 64); Ap += __shfl_xor(Ap, 16, 64);
        Bp += __shfl_xor(Bp, 16, 64); Cp += __shfl_xor(Cp, 16, 64);
        Pp += __shfl_xor(Pp, 32, 64); Qq += __shfl_xor(Qq, 32, 64);
        Aa += __shfl_xor(Aa, 32, 64); Bb += __shfl_xor(Bb, 32, 64);
        Cc += __shfl_xor(Cc, 32, 64); Ap += __shfl_xor(Ap, 32, 64);
        Bp += __shfl_xor(Bp, 32, 64); Cp += __shfl_xor(Cp, 32, 64);

        if (lane < 16) {
            float Gx = env * Aa, Gy = env * Bb, Gz = env * Cc;
            float genv = Pp + rhx * Aa + rhy * Bb + rhz * Cc;
            float pc = env * (Qq + rhx * Ap + rhy * Bp + rhz * Cp) + genv * denv;
            float dotg = Gx * rhx + Gy * rhy + Gz * rhz;
            float cx = pc * rhx + (Gx - dotg * rhx) * rinv;
            float cy = pc * rhy + (Gy - dotg * rhy) * rinv;
            float cz = pc * rhz + (Gz - dotg * rhz) * rinv;

            const float SC = EV2KJ_C * NM2A_C;
            // src-side: coalesced per-edge force record (dst-order position)
            if (valid) fbuf[p_e] = make_float4(SC * cx, SC * cy, SC * cz, 0.0f);

            // segmented inclusive scan over contiguous dst runs (16 edges)
            int kk = key;
            #pragma unroll
            for (int d = 1; d < 16; d <<= 1) {
                float ux = __shfl_up(cx, d, 32);
                float uy = __shfl_up(cy, d, 32);
                float uz = __shfl_up(cz, d, 32);
                int uk = __shfl_up(kk, d, 32);
                if (l16 >= d && uk == kk) { cx += ux; cy += uy; cz += uz; }
            }
            int nk = __shfl_down(kk, 1, 32);
            bool leader = (l16 == 15) || (nk != kk);
            if (valid && leader) {
                unsafeAtomicAdd(&forces[(size_t)dstI * 3 + 0], -SC * cx);
                unsafeAtomicAdd(&forces[(size_t)dstI * 3 + 1], -SC * cy);
                unsafeAtomicAdd(&forces[(size_t)dstI * 3 + 2], -SC * cz);
            }
        }
    }
}

// ------- src gather via src-bins: LDS per-atom accumulation, few contiguous atomics -------
__global__ __launch_bounds__(256) void gather_src(
    float* __restrict__ forces, const int* __restrict__ sbbase,
    const int2* __restrict__ srcbin, const float4* __restrict__ fbuf,
    int ssh, int N)
{
    __shared__ float acc[3072];   // 1024 atoms x 3
    const int wg = blockIdx.x;
    const int b = wg / GSPLIT, part = wg % GSPLIT;
    const int base = sbbase[b];
    const int cnt = sbbase[b + 1] - base;
    const int r0 = base + (int)((long long)cnt * part / GSPLIT);
    const int r1 = base + (int)((long long)cnt * (part + 1) / GSPLIT);
    const int abase = b << ssh;
    const bool lok = (ssh <= 10);
    for (int i = threadIdx.x; i < 3072; i += 256) acc[i] = 0.f;
    __syncthreads();
    for (int i = r0 + threadIdx.x; i < r1; i += 256) {
        int2 r = srcbin[i];
        float4 f = fbuf[r.y];
        if (lok) {
            int la = r.x - abase;
            atomicAdd(&acc[la * 3 + 0], f.x);
            atomicAdd(&acc[la * 3 + 1], f.y);
            atomicAdd(&acc[la * 3 + 2], f.z);
        } else {
            unsafeAtomicAdd(&forces[(size_t)r.x * 3 + 0], f.x);
            unsafeAtomicAdd(&forces[(size_t)r.x * 3 + 1], f.y);
            unsafeAtomicAdd(&forces[(size_t)r.x * 3 + 2], f.z);
        }
    }
    __syncthreads();
    if (lok) {
        for (int la = threadIdx.x; la < 1024; la += 256) {
            int a = abase + la;
            if (a < N) {
                float ax = acc[la * 3 + 0], ay = acc[la * 3 + 1], az = acc[la * 3 + 2];
                if (ax != 0.f || ay != 0.f || az != 0.f) {
                    unsafeAtomicAdd(&forces[(size_t)a * 3 + 0], ax);
                    unsafeAtomicAdd(&forces[(size_t)a * 3 + 1], ay);
                    unsafeAtomicAdd(&forces[(size_t)a * 3 + 2], az);
                }
            }
        }
    }
}

// ---------------- reductions & correction ----------------
__global__ __launch_bounds__(256) void reduce_net(
    const float* __restrict__ f, const float* __restrict__ masses,
    float* __restrict__ accum, int N)
{
    float nx = 0, ny = 0, nz = 0, ms = 0;
    for (int i = blockIdx.x * 256 + threadIdx.x; i < N; i += gridDim.x * 256) {
        nx += f[i * 3 + 0]; ny += f[i * 3 + 1]; nz += f[i * 3 + 2]; ms += masses[i];
    }
    #pragma unroll
    for (int m = 32; m; m >>= 1) {
        nx += __shfl_xor(nx, m, 64);
        ny += __shfl_xor(ny, m, 64);
        nz += __shfl_xor(nz, m, 64);
        ms += __shfl_xor(ms, m, 64);
    }
    __shared__ float red[4][4];
    int w = threadIdx.x >> 6;
    if ((threadIdx.x & 63) == 0) { red[w][0] = nx; red[w][1] = ny; red[w][2] = nz; red[w][3] = ms; }
    __syncthreads();
    if (threadIdx.x == 0) {
        float a0 = 0, a1 = 0, a2 = 0, a3 = 0;
        for (int i = 0; i < 4; i++) { a0 += red[i][0]; a1 += red[i][1]; a2 += red[i][2]; a3 += red[i][3]; }
        unsafeAtomicAdd(accum + 0, a0);
        unsafeAtomicAdd(accum + 1, a1);
        unsafeAtomicAdd(accum + 2, a2);
        unsafeAtomicAdd(accum + 3, a3);
    }
}

__global__ __launch_bounds__(256) void correct_forces(
    float* __restrict__ f, const float* __restrict__ masses,
    const float* __restrict__ accum, int N)
{
    int i = blockIdx.x * 256 + threadIdx.x;
    if (i < N) {
        float c = masses[i] / accum[3];
        f[i * 3 + 0] -= c * accum[0];
        f[i * 3 + 1] -= c * accum[1];
        f[i * 3 + 2] -= c * accum[2];
    }
}

extern "C" void kernel_launch(void* const* d_in, const int* in_sizes, int n_in,
                              void* d_out, int out_size, void* d_ws, size_t ws_size,
                              hipStream_t stream)
{
    (void)n_in; (void)ws_size;
    const float* pos    = (const float*)d_in[0];
    const float* masses = (const float*)d_in[1];
    const float* temb   = (const float*)d_in[2];
    const float* Wr1    = (const float*)d_in[3];
    const float* br1    = (const float*)d_in[4];
    const float* Wr2    = (const float*)d_in[5];
    const float* Wself  = (const float*)d_in[6];
    const float* Wo1    = (const float*)d_in[7];
    const float* bo1    = (const float*)d_in[8];
    const float* Wo2    = (const float*)d_in[9];
    const int* types    = (const int*)d_in[10];
    const int* eidx     = (const int*)d_in[11];
    const int N = in_sizes[1];
    const int E = in_sizes[11] / 2;

    float* out = (float*)d_out;
    float* forces = out + 1;

    // bucket geometry (dst buckets <=512, src buckets <=64)
    int dsh = 7;  while (((N + (1 << dsh) - 1) >> dsh) > 512) dsh++;
    int nbd = (N + (1 << dsh) - 1) >> dsh;
    int ssh = 10; while (((N + (1 << ssh) - 1) >> ssh) > 64) ssh++;
    int nbs = (N + (1 << ssh) - 1) >> ssh;

    float* ws = (float*)d_ws;
    float* s_acc = ws;                               // N*32
    float* v_acc = s_acc + (size_t)N * FDIM;         // N*96
    float* g_all = v_acc + (size_t)N * 96;           // N*128
    float* accum = g_all + (size_t)N * 128;          // 4
    int* meta = (int*)(accum + 4);
    int* dbcnt  = meta;                              // 512
    int* sbcnt  = dbcnt + 512;                       // 64
    int* dbcur  = sbcnt + 64;                        // 512
    int* sbcur  = dbcur + 512;                       // 64
    int* dbbase = sbcur + 64;                        // 513
    int* sbbase = dbbase + 513;                      // 65
    int2* order_sd = (int2*)(((uintptr_t)(sbbase + 65) + 15) & ~(uintptr_t)15);  // E
    int2* srcbin   = order_sd + E;                                               // E
    float4* fbuf   = (float4*)(((uintptr_t)(srcbin + E) + 15) & ~(uintptr_t)15); // E
    _Float16* wpack = (_Float16*)(fbuf + E);                                     // 8KB

    hipMemsetAsync(d_out, 0, (size_t)out_size * sizeof(float), stream);
    hipMemsetAsync(s_acc, 0, (size_t)N * 128 * sizeof(float), stream);
    hipMemsetAsync(meta, 0, 1152 * sizeof(int), stream);   // dbcnt|sbcnt|dbcur|sbcur
    hipMemsetAsync(accum, 0, 4 * sizeof(float), stream);

    hist_buckets<<<512, 256, 0, stream>>>(eidx, dbcnt, sbcnt, E, dsh, ssh, nbd, nbs);
    scan_bases<<<1, 512, 0, stream>>>(dbcnt, sbcnt, dbbase, sbbase, nbd, nbs);
    int nBin = (E + BINW - 1) / BINW;
    bin_dst<<<nBin, 256, 0, stream>>>(eidx, dbbase, dbcur, order_sd, E, dsh, nbd);
    sort_bucket<<<nbd, 256, 0, stream>>>(order_sd, dbbase, sbcur, sbbase, srcbin, dsh, ssh);
    pack_wfrag<<<1, 64, 0, stream>>>(Wr1, Wr2, wpack);

    int nAtomBlocks = (N + 63) / 64;
    int nFwdBlocks = (E + 127) / 128;
    int nBwdBlocks = (E + 63) / 64;
    edge_fwd_mfma<<<nFwdBlocks, 256, 0, stream>>>(pos, types, order_sd,
                                                  wpack, br1, temb,
                                                  s_acc, v_acc, E);
    atom_mlp<<<nAtomBlocks, 256, 0, stream>>>(types, temb, Wself, Wo1, bo1, Wo2,
                                              s_acc, v_acc, g_all, out, N);
    edge_bwd_mfma<<<nBwdBlocks, 256, 0, stream>>>(pos, types, order_sd,
                                                  wpack, br1, temb,
                                                  g_all, forces, fbuf, E);
    gather_src<<<nbs * GSPLIT, 256, 0, stream>>>(forces, sbbase, srcbin, fbuf, ssh, N);
    reduce_net<<<64, 256, 0, stream>>>(forces, masses, accum, N);
    correct_forces<<<(N + 255) / 256, 256, 0, stream>>>(forces, masses, accum, N);
}